// Round 5
// baseline (133.785 us; speedup 1.0000x reference)
//
#include <hip/hip_runtime.h>

#define BSZ 512
#define DIM 768
#define KT 32
#define NCH (DIM / KT)   // 24
#define NTYPES 16
#define MARGIN 1.0f
#define NBLK 256

// ---------------------------------------------------------------------------
// Single fused kernel, 256 blocks x 256 threads = exactly 1 block/CU (all
// co-resident -> hand-rolled grid barrier is deadlock-free).
//   Phase 1: 32x32 dist tile per block (dot-form GEMM, double-buffered LDS,
//            norms fused via shfl_xor over the 8 staging lanes per row).
//   Grid barrier: device-scope release add + acquire spin (+ __threadfence
//            for cross-XCD L2 visibility of the dist tiles).
//   Phase 2: 2 anchors per block: ballot-compact pos/neg, scan |P|x|N| pairs.
//   Phase 3: last block (ticket) finalizes: exact integer V, invalid
//            triplets contribute exactly margin (reference adds margin
//            pre-clamp), one global write.
// ctrl/accum zeroed by a 16 B hipMemsetAsync before launch (ws is poisoned).
// ---------------------------------------------------------------------------
__global__ __launch_bounds__(256) void fused_kernel(
    const float* __restrict__ emb, const int* __restrict__ types,
    float* __restrict__ dist, double* __restrict__ accum,
    unsigned* __restrict__ ctrl,   // ctrl[0]=arrive, ctrl[1]=ticket
    float* __restrict__ out)
{
    const int tid = threadIdx.x;
    const int tx = tid & 15, ty = tid >> 4;
    const int blk = blockIdx.x;
    const int i0 = (blk >> 4) * 32, j0 = (blk & 15) * 32;

    __shared__ float sA[2][KT][34];
    __shared__ float sB[2][KT][34];
    __shared__ float sNA[32], sNB[32];
    __shared__ float pos[BSZ], neg[BSZ];
    __shared__ int npos, nneg;
    __shared__ float wsum[4];
    __shared__ int winner;
    __shared__ int cnt[NTYPES];

    // ---------------- phase 1: dist tile ----------------
    {
        const int li = tid >> 3;   // 0..31 row within tile
        const int kg = tid & 7;    // 0..7  16B group within chunk
        const float* gA = emb + (size_t)(i0 + li) * DIM + 4 * kg;
        const float* gB = emb + (size_t)(j0 + li) * DIM + 4 * kg;

        float4 pa = *(const float4*)gA;
        float4 pb = *(const float4*)gB;
        float na = pa.x * pa.x + pa.y * pa.y + pa.z * pa.z + pa.w * pa.w;
        float nb = pb.x * pb.x + pb.y * pb.y + pb.z * pb.z + pb.w * pb.w;
        sA[0][4 * kg + 0][li] = pa.x; sA[0][4 * kg + 1][li] = pa.y;
        sA[0][4 * kg + 2][li] = pa.z; sA[0][4 * kg + 3][li] = pa.w;
        sB[0][4 * kg + 0][li] = pb.x; sB[0][4 * kg + 1][li] = pb.y;
        sB[0][4 * kg + 2][li] = pb.z; sB[0][4 * kg + 3][li] = pb.w;
        __syncthreads();

        float a00 = 0.f, a01 = 0.f, a10 = 0.f, a11 = 0.f;

        for (int c = 0; c < NCH; ++c) {
            const int cur = c & 1;
            float4 qa, qb;
            if (c + 1 < NCH) {
                qa = *(const float4*)(gA + (c + 1) * KT);
                qb = *(const float4*)(gB + (c + 1) * KT);
            }
            #pragma unroll
            for (int k = 0; k < KT; ++k) {
                float2 av = *(const float2*)&sA[cur][k][2 * ty];
                float2 bv = *(const float2*)&sB[cur][k][2 * tx];
                a00 = fmaf(av.x, bv.x, a00);
                a01 = fmaf(av.x, bv.y, a01);
                a10 = fmaf(av.y, bv.x, a10);
                a11 = fmaf(av.y, bv.y, a11);
            }
            if (c + 1 < NCH) {
                na += qa.x * qa.x + qa.y * qa.y + qa.z * qa.z + qa.w * qa.w;
                nb += qb.x * qb.x + qb.y * qb.y + qb.z * qb.z + qb.w * qb.w;
                const int nxt = 1 - cur;
                sA[nxt][4 * kg + 0][li] = qa.x; sA[nxt][4 * kg + 1][li] = qa.y;
                sA[nxt][4 * kg + 2][li] = qa.z; sA[nxt][4 * kg + 3][li] = qa.w;
                sB[nxt][4 * kg + 0][li] = qb.x; sB[nxt][4 * kg + 1][li] = qb.y;
                sB[nxt][4 * kg + 2][li] = qb.z; sB[nxt][4 * kg + 3][li] = qb.w;
            }
            __syncthreads();
        }

        #pragma unroll
        for (int off = 1; off < 8; off <<= 1) {
            na += __shfl_xor(na, off);
            nb += __shfl_xor(nb, off);
        }
        if (kg == 0) { sNA[li] = na; sNB[li] = nb; }
        __syncthreads();

        const float nA0 = sNA[2 * ty], nA1 = sNA[2 * ty + 1];
        const float nB0 = sNB[2 * tx], nB1 = sNB[2 * tx + 1];
        float2 o0, o1;
        o0.x = sqrtf(fmaxf(nA0 + nB0 - 2.f * a00, 0.f));
        o0.y = sqrtf(fmaxf(nA0 + nB1 - 2.f * a01, 0.f));
        o1.x = sqrtf(fmaxf(nA1 + nB0 - 2.f * a10, 0.f));
        o1.y = sqrtf(fmaxf(nA1 + nB1 - 2.f * a11, 0.f));
        const int r0 = i0 + 2 * ty, c0 = j0 + 2 * tx;
        *(float2*)&dist[(size_t)r0 * BSZ + c0] = o0;
        *(float2*)&dist[(size_t)(r0 + 1) * BSZ + c0] = o1;
    }

    // ---------------- grid barrier (all 256 blocks co-resident) ------------
    __syncthreads();
    __threadfence();                       // flush dist tiles device-wide
    if (tid == 0) {
        __hip_atomic_fetch_add(&ctrl[0], 1u, __ATOMIC_RELEASE,
                               __HIP_MEMORY_SCOPE_AGENT);
        while (__hip_atomic_load(&ctrl[0], __ATOMIC_ACQUIRE,
                                 __HIP_MEMORY_SCOPE_AGENT) < NBLK)
            __builtin_amdgcn_s_sleep(2);
    }
    __syncthreads();
    __threadfence();                       // acquire side: invalidate stale

    // ---------------- phase 2: 2 anchors per block --------------------------
    const int lane = tid & 63;
    double blocksum = 0.0;
    for (int ai = 0; ai < 2; ++ai) {
        const int a = blk * 2 + ai;
        if (tid == 0) { npos = 0; nneg = 0; }
        const int ta = types[a];
        __syncthreads();

        for (int j = tid; j < BSZ; j += 256) {
            const float d = dist[(size_t)a * BSZ + j];
            const bool isp = (types[j] == ta);
            const unsigned long long m = __ballot(isp);
            const unsigned long long below = m & ((1ull << lane) - 1ull);
            const int cp = __popcll(m);
            int basep = 0, basen = 0;
            if (lane == 0) {
                basep = atomicAdd(&npos, cp);
                basen = atomicAdd(&nneg, 64 - cp);
            }
            basep = __shfl(basep, 0);
            basen = __shfl(basen, 0);
            const int pbelow = (int)__popcll(below);
            if (isp) pos[basep + pbelow] = d;
            else     neg[basen + (lane - pbelow)] = d;
        }
        __syncthreads();
        const int np = npos, nn = nneg;

        float local = 0.f;
        for (int pi = 0; pi < np; ++pi) {
            const float dpm = pos[pi] + MARGIN;     // broadcast LDS read
            for (int n = tid; n < nn; n += 256)
                local += fmaxf(dpm - neg[n], 0.f);
        }

        #pragma unroll
        for (int off = 32; off > 0; off >>= 1) local += __shfl_down(local, off);
        if (lane == 0) wsum[tid >> 6] = local;
        __syncthreads();
        if (tid == 0)
            blocksum += (double)wsum[0] + (double)wsum[1]
                      + (double)wsum[2] + (double)wsum[3];
        __syncthreads();   // protect wsum/npos reuse next iteration
    }
    if (tid == 0) atomicAdd(accum, blocksum);

    // ---------------- phase 3: last block finalizes --------------------------
    if (tid == 0) {
        unsigned t = __hip_atomic_fetch_add(&ctrl[1], 1u, __ATOMIC_ACQ_REL,
                                            __HIP_MEMORY_SCOPE_AGENT);
        winner = (t == NBLK - 1) ? 1 : 0;
    }
    __syncthreads();
    if (winner) {                          // block-uniform branch
        if (tid < NTYPES) cnt[tid] = 0;
        __syncthreads();
        for (int i = tid; i < BSZ; i += 256) atomicAdd(&cnt[types[i]], 1);
        __syncthreads();
        if (tid == 0) {
            long long V = 0;
            for (int t2 = 0; t2 < NTYPES; t2++) {
                long long c = cnt[t2];
                V += c * c * (long long)(BSZ - c);
            }
            const long long B3 = (long long)BSZ * BSZ * BSZ;
            double total = __hip_atomic_load(accum, __ATOMIC_ACQUIRE,
                                             __HIP_MEMORY_SCOPE_AGENT)
                         + (double)(B3 - V) * (double)MARGIN;
            out[0] = (float)(total / (double)V);
        }
    }
}

extern "C" void kernel_launch(void* const* d_in, const int* in_sizes, int n_in,
                              void* d_out, int out_size, void* d_ws, size_t ws_size,
                              hipStream_t stream) {
    const int* types = (const int*)d_in[0];
    const float* emb = (const float*)d_in[1];
    float* out = (float*)d_out;

    float* dist = (float*)d_ws;
    char* tail = (char*)d_ws + (size_t)BSZ * BSZ * sizeof(float);
    double* accum = (double*)tail;             // 8 B
    unsigned* ctrl = (unsigned*)(tail + 8);    // 8 B (arrive, ticket)

    hipMemsetAsync(tail, 0, 16, stream);       // zero accum + ctrl (capturable)
    fused_kernel<<<NBLK, 256, 0, stream>>>(emb, types, dist, accum, ctrl, out);
}

// Round 6
// 80.329 us; speedup vs baseline: 1.6655x; 1.6655x over previous
//
#include <hip/hip_runtime.h>

#define BSZ 512
#define DIM 768
#define KSPLIT 4
#define KSEG (DIM / KSPLIT)   // 192
#define KT 32
#define NCHK (KSEG / KT)      // 6
#define TILE 64
#define NTYPES 16
#define MARGIN 1.0f

// ---------------------------------------------------------------------------
// Kernel 1: K-split partial dot matrices.  grid = 256 = 4 ksplits x 64 tiles
// (one block per CU).  Each block: 64x64 tile, 192-wide K segment, 16x16
// threads, 4x4 micro-tile -> per k: 2 ds_read_b128 feed 16 FMAs (4x fewer
// LDS instructions per FMA than the 2x2 R4 kernel, which was LDS-issue
// bound).  Double-buffered LDS, k-major layout, pad +4 floats (16B-aligned,
// 2-way bank alias at worst = free).  Diagonal tiles also store their
// partial diagonal: diag of the summed dot matrix == squared norms, so no
// separate norms pass is needed.  No device fences anywhere — kernel
// boundaries provide coherence (R5 showed agent-scope fences cost ~40us).
// ---------------------------------------------------------------------------
__global__ __launch_bounds__(256) void dot_partial_kernel(
    const float* __restrict__ emb,
    float* __restrict__ part,       // [KSPLIT][BSZ][BSZ]
    float* __restrict__ ndiag,      // [KSPLIT][BSZ]
    double* __restrict__ accum)
{
    const int tid = threadIdx.x;
    const int tx = tid & 15, ty = tid >> 4;
    const int blk = blockIdx.x;
    const int ks = blk >> 6;          // 0..3
    const int tile = blk & 63;        // 0..63
    const int ti = tile >> 3, tj = tile & 7;
    const int i0 = ti * TILE, j0 = tj * TILE;

    if (blk == 0 && tid == 0) *accum = 0.0;   // ws is poisoned each launch

    __shared__ float sA[2][KT][TILE + 4];
    __shared__ float sB[2][KT][TILE + 4];

    // staging: row = tid>>2 (0..63), g = tid&3 -> float4 groups g and g+4
    const int srow = tid >> 2;
    const int g = tid & 3;
    const float* gA = emb + (size_t)(i0 + srow) * DIM + ks * KSEG;
    const float* gB = emb + (size_t)(j0 + srow) * DIM + ks * KSEG;

    float4 a0 = *(const float4*)(gA + 4 * g);
    float4 a1 = *(const float4*)(gA + 4 * (g + 4));
    float4 b0 = *(const float4*)(gB + 4 * g);
    float4 b1 = *(const float4*)(gB + 4 * (g + 4));

    {
        float (*pA)[TILE + 4] = sA[0];
        float (*pB)[TILE + 4] = sB[0];
        pA[4*g+0][srow]=a0.x; pA[4*g+1][srow]=a0.y; pA[4*g+2][srow]=a0.z; pA[4*g+3][srow]=a0.w;
        pA[4*(g+4)+0][srow]=a1.x; pA[4*(g+4)+1][srow]=a1.y; pA[4*(g+4)+2][srow]=a1.z; pA[4*(g+4)+3][srow]=a1.w;
        pB[4*g+0][srow]=b0.x; pB[4*g+1][srow]=b0.y; pB[4*g+2][srow]=b0.z; pB[4*g+3][srow]=b0.w;
        pB[4*(g+4)+0][srow]=b1.x; pB[4*(g+4)+1][srow]=b1.y; pB[4*(g+4)+2][srow]=b1.z; pB[4*(g+4)+3][srow]=b1.w;
    }
    __syncthreads();

    float acc[4][4] = {};

    for (int c = 0; c < NCHK; ++c) {
        const int cur = c & 1;
        float4 qa0, qa1, qb0, qb1;
        if (c + 1 < NCHK) {
            const float* pa = gA + (c + 1) * KT;
            const float* pb = gB + (c + 1) * KT;
            qa0 = *(const float4*)(pa + 4 * g);
            qa1 = *(const float4*)(pa + 4 * (g + 4));
            qb0 = *(const float4*)(pb + 4 * g);
            qb1 = *(const float4*)(pb + 4 * (g + 4));
        }
        #pragma unroll
        for (int k = 0; k < KT; ++k) {
            float4 av = *(const float4*)&sA[cur][k][4 * ty];
            float4 bv = *(const float4*)&sB[cur][k][4 * tx];
            acc[0][0] = fmaf(av.x, bv.x, acc[0][0]);
            acc[0][1] = fmaf(av.x, bv.y, acc[0][1]);
            acc[0][2] = fmaf(av.x, bv.z, acc[0][2]);
            acc[0][3] = fmaf(av.x, bv.w, acc[0][3]);
            acc[1][0] = fmaf(av.y, bv.x, acc[1][0]);
            acc[1][1] = fmaf(av.y, bv.y, acc[1][1]);
            acc[1][2] = fmaf(av.y, bv.z, acc[1][2]);
            acc[1][3] = fmaf(av.y, bv.w, acc[1][3]);
            acc[2][0] = fmaf(av.z, bv.x, acc[2][0]);
            acc[2][1] = fmaf(av.z, bv.y, acc[2][1]);
            acc[2][2] = fmaf(av.z, bv.z, acc[2][2]);
            acc[2][3] = fmaf(av.z, bv.w, acc[2][3]);
            acc[3][0] = fmaf(av.w, bv.x, acc[3][0]);
            acc[3][1] = fmaf(av.w, bv.y, acc[3][1]);
            acc[3][2] = fmaf(av.w, bv.z, acc[3][2]);
            acc[3][3] = fmaf(av.w, bv.w, acc[3][3]);
        }
        if (c + 1 < NCHK) {
            float (*pA)[TILE + 4] = sA[1 - cur];
            float (*pB)[TILE + 4] = sB[1 - cur];
            pA[4*g+0][srow]=qa0.x; pA[4*g+1][srow]=qa0.y; pA[4*g+2][srow]=qa0.z; pA[4*g+3][srow]=qa0.w;
            pA[4*(g+4)+0][srow]=qa1.x; pA[4*(g+4)+1][srow]=qa1.y; pA[4*(g+4)+2][srow]=qa1.z; pA[4*(g+4)+3][srow]=qa1.w;
            pB[4*g+0][srow]=qb0.x; pB[4*g+1][srow]=qb0.y; pB[4*g+2][srow]=qb0.z; pB[4*g+3][srow]=qb0.w;
            pB[4*(g+4)+0][srow]=qb1.x; pB[4*(g+4)+1][srow]=qb1.y; pB[4*(g+4)+2][srow]=qb1.z; pB[4*(g+4)+3][srow]=qb1.w;
        }
        __syncthreads();
    }

    // store 4x4 partial tile (coalesced float4 per row)
    float* pbuf = part + (size_t)ks * BSZ * BSZ;
    #pragma unroll
    for (int r = 0; r < 4; ++r) {
        const int gi = i0 + 4 * ty + r;
        float4 v = make_float4(acc[r][0], acc[r][1], acc[r][2], acc[r][3]);
        *(float4*)&pbuf[(size_t)gi * BSZ + j0 + 4 * tx] = v;
    }
    // diagonal tiles: partial diagonal = partial squared norms
    if (ti == tj && tx == ty) {
        #pragma unroll
        for (int r = 0; r < 4; ++r)
            ndiag[ks * BSZ + i0 + 4 * ty + r] = acc[r][r];
    }
}

// ---------------------------------------------------------------------------
// Kernel 2: per-anchor triplet sum.  Sums the 4 K-split partials + forms the
// distance on the fly (norms from summed ndiag, staged in LDS), then the
// proven ballot-compaction + |P|x|N| scan.  512 blocks = 2/CU.
// ---------------------------------------------------------------------------
__global__ __launch_bounds__(256) void triplet_kernel(
    const float* __restrict__ part, const float* __restrict__ ndiag,
    const int* __restrict__ types, double* __restrict__ accum)
{
    const int a = blockIdx.x;
    const int tid = threadIdx.x;
    const int lane = tid & 63;
    __shared__ float nrm[BSZ];
    __shared__ float pos[BSZ], neg[BSZ];
    __shared__ int npos, nneg;
    __shared__ float wsum[4];
    if (tid == 0) { npos = 0; nneg = 0; }
    for (int j = tid; j < BSZ; j += 256)
        nrm[j] = ndiag[j] + ndiag[BSZ + j] + ndiag[2 * BSZ + j] + ndiag[3 * BSZ + j];
    const int ta = types[a];
    __syncthreads();

    const float na = nrm[a];
    const size_t rb = (size_t)a * BSZ;
    const size_t PS = (size_t)BSZ * BSZ;

    for (int j = tid; j < BSZ; j += 256) {
        const float sp = part[rb + j] + part[PS + rb + j]
                       + part[2 * PS + rb + j] + part[3 * PS + rb + j];
        const float d = sqrtf(fmaxf(na + nrm[j] - 2.f * sp, 0.f));
        const bool isp = (types[j] == ta);
        const unsigned long long m = __ballot(isp);
        const unsigned long long below = m & ((1ull << lane) - 1ull);
        const int cp = __popcll(m);
        int basep = 0, basen = 0;
        if (lane == 0) {
            basep = atomicAdd(&npos, cp);
            basen = atomicAdd(&nneg, 64 - cp);
        }
        basep = __shfl(basep, 0);
        basen = __shfl(basen, 0);
        const int pbelow = (int)__popcll(below);
        if (isp) pos[basep + pbelow] = d;
        else     neg[basen + (lane - pbelow)] = d;
    }
    __syncthreads();
    const int np = npos, nn = nneg;

    float local = 0.f;
    for (int pi = 0; pi < np; ++pi) {
        const float dpm = pos[pi] + MARGIN;          // broadcast LDS read
        for (int n = tid; n < nn; n += 256)
            local += fmaxf(dpm - neg[n], 0.f);
    }

    #pragma unroll
    for (int off = 32; off > 0; off >>= 1) local += __shfl_down(local, off);
    if (lane == 0) wsum[tid >> 6] = local;
    __syncthreads();
    if (tid == 0) {
        double s = (double)wsum[0] + (double)wsum[1] + (double)wsum[2] + (double)wsum[3];
        atomicAdd(accum, s);
    }
}

// ---------------------------------------------------------------------------
// Kernel 3: finalize.  Exact integer V = sum_t c_t^2 (B - c_t); each invalid
// triplet contributes exactly margin (reference adds margin pre-clamp).
// ---------------------------------------------------------------------------
__global__ void finalize_kernel(const int* __restrict__ types,
                                const double* __restrict__ accum,
                                float* __restrict__ out) {
    __shared__ int cnt[NTYPES];
    if (threadIdx.x < NTYPES) cnt[threadIdx.x] = 0;
    __syncthreads();
    for (int i = threadIdx.x; i < BSZ; i += blockDim.x) atomicAdd(&cnt[types[i]], 1);
    __syncthreads();
    if (threadIdx.x == 0) {
        long long V = 0;
        for (int t = 0; t < NTYPES; t++) {
            long long c = cnt[t];
            V += c * c * (long long)(BSZ - c);
        }
        const long long B3 = (long long)BSZ * BSZ * BSZ;
        double total = *accum + (double)(B3 - V) * (double)MARGIN;
        out[0] = (float)(total / (double)V);
    }
}

extern "C" void kernel_launch(void* const* d_in, const int* in_sizes, int n_in,
                              void* d_out, int out_size, void* d_ws, size_t ws_size,
                              hipStream_t stream) {
    const int* types = (const int*)d_in[0];
    const float* emb = (const float*)d_in[1];
    float* out = (float*)d_out;

    float* part = (float*)d_ws;                               // 4 MB
    float* ndiag = part + (size_t)KSPLIT * BSZ * BSZ;         // 8 KB
    double* accum = (double*)(ndiag + KSPLIT * BSZ);          // 8 B

    dot_partial_kernel<<<256, 256, 0, stream>>>(emb, part, ndiag, accum);
    triplet_kernel<<<BSZ, 256, 0, stream>>>(part, ndiag, types, accum);
    finalize_kernel<<<1, 256, 0, stream>>>(types, accum, out);
}